// Round 4
// baseline (116.719 us; speedup 1.0000x reference)
//
#include <hip/hip_runtime.h>

#define NI 12   // input props
#define NR 6    // rules
#define NJ 2    // templates per rule
#define NL 2    // feature width
#define NV 4    // variables

typedef float v2f __attribute__((ext_vector_type(2)));

// exp2(n) on n in [-2, 0], degree-4 poly, abs err ~1e-4. Match scores give
// n in [-1.74, 0] (w<=0.6, t,f in [0,1]), so no range reduction needed.
#define EC0 0.9999561f
#define EC1 0.6919824f
#define EC2 0.2353942f
#define EC3 0.0482908f
#define EC4 0.0049248f

// 256 threads, 512 batch elements per block: thread t handles elements
// (blockIdx*512 + t) and (blockIdx*512 + t + 256). Params are computed once
// per block into LDS and broadcast-read (wave-uniform addresses).
__global__ __launch_bounds__(256) void
abstraction_fused(const float4* __restrict__ feat4,
                  const float* __restrict__ templates,
                  const float* __restrict__ gammas,
                  const float* __restrict__ body_W,
                  const float* __restrict__ body_b,
                  const float* __restrict__ head_W,
                  const float* __restrict__ head_b,
                  float4* __restrict__ out4, int B) {
    __shared__ __align__(16) float sG[NR * NJ * 5];           // A0,A1,W0,W1,Cn per (r,j)
    __shared__ __align__(16) float sMt[NR * NJ * NL * NL];    // [r][j][lp][l] fused matrix
    __shared__ __align__(16) float sC[NR * NL];               // fused bias

    const int t = threadIdx.x;
    const float LOG2E = 1.4426950408889634f;

    // ---- derived parameters into LDS (redundant per block, tiny) ----
    if (t < NR * NJ) {
        const int g = t;
        float g0 = fminf(fmaxf(gammas[g * NL + 0], 0.f), 1.f);
        float g1 = fminf(fmaxf(gammas[g * NL + 1], 0.f), 1.f);
        float w0 = 1.f - g0, w1 = 1.f - g1;
        float t0 = templates[g * NL + 0], t1 = templates[g * NL + 1];
        float wt0 = w0 * t0, wt1 = w1 * t1;
        float c0 = wt0 * t0 + wt1 * t1;
        sG[g * 5 + 0] = 2.f * LOG2E * wt0;
        sG[g * 5 + 1] = 2.f * LOG2E * wt1;
        sG[g * 5 + 2] = -LOG2E * w0;
        sG[g * 5 + 3] = -LOG2E * w1;
        sG[g * 5 + 4] = -LOG2E * c0;
    } else if (t >= 64 && t < 64 + NR * NL) {
        const int idx = t - 64;
        const int r = idx >> 1, l = idx & 1;
        float acc = head_b[r * NL + l];
        #pragma unroll
        for (int v = 0; v < NV; ++v) {
            float bs = body_b[(r * NJ + 0) * NV + v] + body_b[(r * NJ + 1) * NV + v];
            acc = fmaf(head_W[(r * NL + l) * NV + v], bs, acc);
        }
        sC[idx] = acc;
    } else if (t >= 128 && t < 128 + NR * NJ * NL * NL) {
        // sMt[((r*2+j)*2+lp)*2+l] = sum_v head_W[r,l,v]*body_W[r,j,v,lp]
        const int idx = t - 128;
        const int l = idx & 1, lp = (idx >> 1) & 1, j = (idx >> 2) & 1, r = idx >> 3;
        float acc = 0.f;
        #pragma unroll
        for (int v = 0; v < NV; ++v)
            acc = fmaf(head_W[(r * NL + l) * NV + v],
                       body_W[((r * NJ + j) * NV + v) * NL + lp], acc);
        sMt[idx] = acc;
    }
    __syncthreads();

    const int e0 = blockIdx.x * 512 + t;
    const int e1 = e0 + 256;

    // ---- issue all 12 loads up front (12 outstanding vmem ops/wave) ----
    const int maxIdx4 = B * 6 - 1;
    float4 va[6], vb[6];
    #pragma unroll
    for (int k = 0; k < 6; ++k) {
        int gi = e0 * 6 + k; if (gi > maxIdx4) gi = maxIdx4;
        va[k] = feat4[gi];
    }
    #pragma unroll
    for (int k = 0; k < 6; ++k) {
        int gi = e1 * 6 + k; if (gi > maxIdx4) gi = maxIdx4;
        vb[k] = feat4[gi];
    }

    float f0a[NI], f1a[NI], f0b[NI], f1b[NI];
    #pragma unroll
    for (int k = 0; k < 6; ++k) {
        f0a[2 * k + 0] = va[k].x; f1a[2 * k + 0] = va[k].y;
        f0a[2 * k + 1] = va[k].z; f1a[2 * k + 1] = va[k].w;
        f0b[2 * k + 0] = vb[k].x; f1b[2 * k + 0] = vb[k].y;
        f0b[2 * k + 1] = vb[k].z; f1b[2 * k + 1] = vb[k].w;
    }

    const v2f C0v = EC0, C1v = EC1, C2v = EC2, C3v = EC3, C4v = EC4;
    float oa[NR * NL], ob[NR * NL];

    #pragma unroll
    for (int r = 0; r < NR; ++r) {
        v2f Oa = *(const v2f*)&sC[r * 2];
        v2f Ob = Oa;
        #pragma unroll
        for (int j = 0; j < NJ; ++j) {
            const int g = r * NJ + j;
            const v2f A0 = sG[g * 5 + 0];
            const v2f A1 = sG[g * 5 + 1];
            const v2f W0 = sG[g * 5 + 2];
            const v2f W1 = sG[g * 5 + 3];
            const v2f Cn = sG[g * 5 + 4];
            v2f dena = 0.f, a0a = 0.f, a1a = 0.f;
            v2f denb = 0.f, a0b = 0.f, a1b = 0.f;
            #pragma unroll
            for (int i = 0; i < NI; i += 2) {
                v2f X0a = { f0a[i], f0a[i + 1] };
                v2f X1a = { f1a[i], f1a[i + 1] };
                v2f X0b = { f0b[i], f0b[i + 1] };
                v2f X1b = { f1b[i], f1b[i + 1] };
                v2f na = __builtin_elementwise_fma(
                             X0a, __builtin_elementwise_fma(W0, X0a, A0),
                             __builtin_elementwise_fma(
                                 X1a, __builtin_elementwise_fma(W1, X1a, A1), Cn));
                v2f nb = __builtin_elementwise_fma(
                             X0b, __builtin_elementwise_fma(W0, X0b, A0),
                             __builtin_elementwise_fma(
                                 X1b, __builtin_elementwise_fma(W1, X1b, A1), Cn));
                v2f pa = __builtin_elementwise_fma(
                             na, __builtin_elementwise_fma(
                                 na, __builtin_elementwise_fma(
                                     na, __builtin_elementwise_fma(na, C4v, C3v),
                                     C2v), C1v), C0v);
                v2f pb = __builtin_elementwise_fma(
                             nb, __builtin_elementwise_fma(
                                 nb, __builtin_elementwise_fma(
                                     nb, __builtin_elementwise_fma(nb, C4v, C3v),
                                     C2v), C1v), C0v);
                dena += pa; denb += pb;
                a0a = __builtin_elementwise_fma(pa, X0a, a0a);
                a1a = __builtin_elementwise_fma(pa, X1a, a1a);
                a0b = __builtin_elementwise_fma(pb, X0b, a0b);
                a1b = __builtin_elementwise_fma(pb, X1b, a1b);
            }
            const v2f M0 = *(const v2f*)&sMt[((g) * 2 + 0) * 2];  // {m[l=0,lp=0], m[l=1,lp=0]}
            const v2f M1 = *(const v2f*)&sMt[((g) * 2 + 1) * 2];  // {m[l=0,lp=1], m[l=1,lp=1]}

            float da = dena.x + dena.y;
            float ra = __builtin_amdgcn_rcpf(da);
            v2f s0a = (a0a.x + a0a.y) * ra;
            v2f s1a = (a1a.x + a1a.y) * ra;
            Oa = __builtin_elementwise_fma(s0a, M0,
                 __builtin_elementwise_fma(s1a, M1, Oa));

            float db = denb.x + denb.y;
            float rb = __builtin_amdgcn_rcpf(db);
            v2f s0b = (a0b.x + a0b.y) * rb;
            v2f s1b = (a1b.x + a1b.y) * rb;
            Ob = __builtin_elementwise_fma(s0b, M0,
                 __builtin_elementwise_fma(s1b, M1, Ob));
        }
        oa[r * 2 + 0] = Oa.x; oa[r * 2 + 1] = Oa.y;
        ob[r * 2 + 0] = Ob.x; ob[r * 2 + 1] = Ob.y;
    }

    // ---- direct stores: 3 float4 per element ----
    if (e0 < B) {
        float4* p = &out4[(size_t)e0 * 3];
        p[0] = make_float4(oa[0], oa[1], oa[2], oa[3]);
        p[1] = make_float4(oa[4], oa[5], oa[6], oa[7]);
        p[2] = make_float4(oa[8], oa[9], oa[10], oa[11]);
    }
    if (e1 < B) {
        float4* p = &out4[(size_t)e1 * 3];
        p[0] = make_float4(ob[0], ob[1], ob[2], ob[3]);
        p[1] = make_float4(ob[4], ob[5], ob[6], ob[7]);
        p[2] = make_float4(ob[8], ob[9], ob[10], ob[11]);
    }
}

extern "C" void kernel_launch(void* const* d_in, const int* in_sizes, int n_in,
                              void* d_out, int out_size, void* d_ws, size_t ws_size,
                              hipStream_t stream) {
    (void)n_in; (void)out_size; (void)d_ws; (void)ws_size;
    const float4* feat4    = (const float4*)d_in[0];
    const float* templates = (const float*)d_in[1];
    const float* gammas    = (const float*)d_in[2];
    const float* body_W    = (const float*)d_in[3];
    const float* body_b    = (const float*)d_in[4];
    const float* head_W    = (const float*)d_in[5];
    const float* head_b    = (const float*)d_in[6];
    float4* out4 = (float4*)d_out;

    int B = in_sizes[0] / (NI * NL);
    int blocks = (B + 511) / 512;
    hipLaunchKernelGGL(abstraction_fused, dim3(blocks), dim3(256), 0, stream,
                       feat4, templates, gammas, body_W, body_b, head_W, head_b,
                       out4, B);
}

// Round 6
// 110.708 us; speedup vs baseline: 1.0543x; 1.0543x over previous
//
#include <hip/hip_runtime.h>

#define NI 12   // input props
#define NR 6    // rules
#define NJ 2    // templates per rule
#define NL 2    // feature width
#define NV 4    // variables

#define BLK 128            // threads per block (2 waves)
#define EPB BLK            // elements per block (1 per thread)

typedef float v2f __attribute__((ext_vector_type(2)));

__global__ __launch_bounds__(BLK) void
abstraction_fused(const float4* __restrict__ feat4,
                  const float* __restrict__ templates,
                  const float* __restrict__ gammas,
                  const float* __restrict__ body_W,
                  const float* __restrict__ body_b,
                  const float* __restrict__ head_W,
                  const float* __restrict__ head_b,
                  float4* __restrict__ out4, int B) {
    // Per-wave staging region: 384 float4 = 6 KB. Input order = DMA natural
    // order (wave-uniform base + lane*16). Reused for output staging.
    __shared__ __align__(16) float4 sF[BLK * 6];
    __shared__ __align__(16) float sG[NR * NJ * 5];         // A0,A1,W0,W1,Cn
    __shared__ __align__(16) float sMt[NR * NJ * NL * NL];  // [r][j][lp][l]
    __shared__ __align__(16) float sC[NR * NL];

    const int t = threadIdx.x;
    const int lane = t & 63;
    const int w = t >> 6;
    const float LOG2E = 1.4426950408889634f;

    const int blockElem0 = blockIdx.x * EPB;
    const bool fullTile = (blockElem0 + EPB) <= B;   // block-uniform

    // ---- issue global->LDS DMA: 6 x 1KB coalesced per wave ----
    if (fullTile) {
        const int base4 = (blockElem0 + w * 64) * 6;     // wave's first float4
        const float4* gp = feat4 + base4 + lane;         // lane-contiguous 16B
        #pragma unroll
        for (int k = 0; k < 6; ++k) {
            __builtin_amdgcn_global_load_lds(
                (const __attribute__((address_space(1))) void*)(gp + k * 64),
                (__attribute__((address_space(3))) void*)&sF[w * 384 + k * 64],
                16, 0, 0);
        }
    }

    // ---- derived parameters (wave 0 only; overlaps with DMA flight) ----
    if (t < NR * NJ) {
        const int g = t;
        float g0 = fminf(fmaxf(gammas[g * NL + 0], 0.f), 1.f);
        float g1 = fminf(fmaxf(gammas[g * NL + 1], 0.f), 1.f);
        float w0 = 1.f - g0, w1 = 1.f - g1;
        float t0 = templates[g * NL + 0], t1 = templates[g * NL + 1];
        float wt0 = w0 * t0, wt1 = w1 * t1;
        float c0 = wt0 * t0 + wt1 * t1;
        sG[g * 5 + 0] = 2.f * LOG2E * wt0;
        sG[g * 5 + 1] = 2.f * LOG2E * wt1;
        sG[g * 5 + 2] = -LOG2E * w0;
        sG[g * 5 + 3] = -LOG2E * w1;
        sG[g * 5 + 4] = -LOG2E * c0;
    } else if (t >= 16 && t < 16 + NR * NL) {
        const int idx = t - 16;
        const int r = idx >> 1, l = idx & 1;
        float acc = head_b[r * NL + l];
        #pragma unroll
        for (int v = 0; v < NV; ++v) {
            float bs = body_b[(r * NJ + 0) * NV + v] + body_b[(r * NJ + 1) * NV + v];
            acc = fmaf(head_W[(r * NL + l) * NV + v], bs, acc);
        }
        sC[idx] = acc;
    } else if (t >= 32 && t < 32 + NR * NJ * NL * NL) {
        // sMt[((r*2+j)*2+lp)*2+l] = sum_v head_W[r,l,v]*body_W[r,j,v,lp]
        const int idx = t - 32;
        const int l = idx & 1, lp = (idx >> 1) & 1, j = (idx >> 2) & 1, r = idx >> 3;
        float acc = 0.f;
        #pragma unroll
        for (int v = 0; v < NV; ++v)
            acc = fmaf(head_W[(r * NL + l) * NV + v],
                       body_W[((r * NJ + j) * NV + v) * NL + lp], acc);
        sMt[idx] = acc;
    }

    // Single barrier: drains vmcnt (DMA complete) + publishes params.
    __syncthreads();

    // ---- features into registers ----
    float f0[NI], f1[NI];
    if (fullTile) {
        #pragma unroll
        for (int k = 0; k < 6; ++k) {
            float4 v = sF[w * 384 + lane * 6 + k];
            f0[2 * k + 0] = v.x; f1[2 * k + 0] = v.y;
            f0[2 * k + 1] = v.z; f1[2 * k + 1] = v.w;
        }
    } else {
        int e = blockElem0 + t; if (e >= B) e = B - 1;
        const float4* fp = feat4 + (size_t)e * 6;
        #pragma unroll
        for (int k = 0; k < 6; ++k) {
            float4 v = fp[k];
            f0[2 * k + 0] = v.x; f1[2 * k + 0] = v.y;
            f0[2 * k + 1] = v.z; f1[2 * k + 1] = v.w;
        }
    }

    // ---- compute (R2 structure: packed fp32 + hw v_exp_f32) ----
    float o[NR * NL];
    #pragma unroll
    for (int r = 0; r < NR; ++r) {
        v2f O = *(const v2f*)&sC[r * 2];
        #pragma unroll
        for (int j = 0; j < NJ; ++j) {
            const int g = r * NJ + j;
            const v2f A0 = sG[g * 5 + 0];
            const v2f A1 = sG[g * 5 + 1];
            const v2f W0 = sG[g * 5 + 2];
            const v2f W1 = sG[g * 5 + 3];
            const v2f Cn = sG[g * 5 + 4];
            v2f den = 0.f, a0 = 0.f, a1 = 0.f;
            #pragma unroll
            for (int i = 0; i < NI; i += 2) {
                v2f X0 = { f0[i], f0[i + 1] };
                v2f X1 = { f1[i], f1[i + 1] };
                v2f n = __builtin_elementwise_fma(
                            X0, __builtin_elementwise_fma(W0, X0, A0),
                            __builtin_elementwise_fma(
                                X1, __builtin_elementwise_fma(W1, X1, A1), Cn));
                v2f p = { __builtin_amdgcn_exp2f(n.x), __builtin_amdgcn_exp2f(n.y) };
                den += p;
                a0 = __builtin_elementwise_fma(p, X0, a0);
                a1 = __builtin_elementwise_fma(p, X1, a1);
            }
            const v2f M0 = *(const v2f*)&sMt[(g * 2 + 0) * 2];
            const v2f M1 = *(const v2f*)&sMt[(g * 2 + 1) * 2];
            float d = den.x + den.y;
            float rinv = __builtin_amdgcn_rcpf(d);
            v2f s0 = (a0.x + a0.y) * rinv;
            v2f s1 = (a1.x + a1.y) * rinv;
            O = __builtin_elementwise_fma(s0, M0,
                __builtin_elementwise_fma(s1, M1, O));
        }
        o[r * 2 + 0] = O.x;
        o[r * 2 + 1] = O.y;
    }

    // ---- stores: stage through per-wave LDS, then coalesced float4 ----
    if (fullTile) {
        // write (48B lane stride = 2-way bank alias = free)
        #pragma unroll
        for (int c = 0; c < 3; ++c)
            sF[w * 384 + lane * 3 + c] =
                make_float4(o[4 * c + 0], o[4 * c + 1], o[4 * c + 2], o[4 * c + 3]);
        // read contiguous + coalesced store (in-order LDS pipe within wave)
        const int outBase4 = (blockElem0 + w * 64) * 3;
        #pragma unroll
        for (int c = 0; c < 3; ++c)
            out4[outBase4 + c * 64 + lane] = sF[w * 384 + c * 64 + lane];
    } else {
        int e = blockElem0 + t;
        if (e < B) {
            float4* p = &out4[(size_t)e * 3];
            p[0] = make_float4(o[0], o[1], o[2], o[3]);
            p[1] = make_float4(o[4], o[5], o[6], o[7]);
            p[2] = make_float4(o[8], o[9], o[10], o[11]);
        }
    }
}

extern "C" void kernel_launch(void* const* d_in, const int* in_sizes, int n_in,
                              void* d_out, int out_size, void* d_ws, size_t ws_size,
                              hipStream_t stream) {
    (void)n_in; (void)out_size; (void)d_ws; (void)ws_size;
    const float4* feat4    = (const float4*)d_in[0];
    const float* templates = (const float*)d_in[1];
    const float* gammas    = (const float*)d_in[2];
    const float* body_W    = (const float*)d_in[3];
    const float* body_b    = (const float*)d_in[4];
    const float* head_W    = (const float*)d_in[5];
    const float* head_b    = (const float*)d_in[6];
    float4* out4 = (float4*)d_out;

    int B = in_sizes[0] / (NI * NL);
    int blocks = (B + EPB - 1) / EPB;
    hipLaunchKernelGGL(abstraction_fused, dim3(blocks), dim3(BLK), 0, stream,
                       feat4, templates, gammas, body_W, body_b, head_W, head_b,
                       out4, B);
}

// Round 7
// 109.964 us; speedup vs baseline: 1.0614x; 1.0068x over previous
//
#include <hip/hip_runtime.h>

#define NI 12   // input props
#define NR 6    // rules
#define NJ 2    // templates per rule
#define NL 2    // feature width
#define NV 4    // variables

typedef float v2f __attribute__((ext_vector_type(2)));

// Single fused kernel. Per-block, the first waves compute the 120 derived
// parameters into LDS (redundant across blocks, ~nothing), then every thread
// handles one batch element.
//
// Derived params:
//  sG[g*5+..] per (r,j) g=r*2+j: A0,A1,W0,W1,Cn with
//     n_i = x0*(W0*x0+A0) + x1*(W1*x1+A1) + Cn   (== -log2e * match_score)
//  sM[((r*2+l)*2+j)*2+lp] = sum_v head_W[r,l,v]*body_W[r,j,v,lp]
//  sC[r*2+l] = head_b[r,l] + sum_v head_W[r,l,v]*(body_b[r,0,v]+body_b[r,1,v])
//
// Session notes (R2..R6 on MI355X):
//  - hw v_exp_f32 beats a degree-4 poly exp2 (trans pipe overlaps other
//    waves' FMA work; poly's +360 main-pipe ops regressed 5-7 us).
//  - LDS staging of loads/stores (incl. global_load_lds DMA) is neutral:
//    inputs are L3-resident after the harness's per-iteration restore, so
//    the strided float4 pattern is not a limiter.
//  - 2 elements/thread regressed (register pressure, no latency win).

__global__ __launch_bounds__(256) void
abstraction_fused(const float* __restrict__ feat,
                  const float* __restrict__ templates,
                  const float* __restrict__ gammas,
                  const float* __restrict__ body_W,
                  const float* __restrict__ body_b,
                  const float* __restrict__ head_W,
                  const float* __restrict__ head_b,
                  float* __restrict__ out, int B) {
    __shared__ float sG[NR * NJ * 5];
    __shared__ float sM[NR * NL * NJ * NL];
    __shared__ float sC[NR * NL];

    const int t = threadIdx.x;
    const float LOG2E = 1.4426950408889634f;

    if (t < NR * NJ) {
        const int g = t;
        float g0 = fminf(fmaxf(gammas[g * NL + 0], 0.f), 1.f);
        float g1 = fminf(fmaxf(gammas[g * NL + 1], 0.f), 1.f);
        float w0 = 1.f - g0, w1 = 1.f - g1;
        float t0 = templates[g * NL + 0], t1 = templates[g * NL + 1];
        float wt0 = w0 * t0, wt1 = w1 * t1;
        float c0 = wt0 * t0 + wt1 * t1;
        sG[g * 5 + 0] = 2.f * LOG2E * wt0;
        sG[g * 5 + 1] = 2.f * LOG2E * wt1;
        sG[g * 5 + 2] = -LOG2E * w0;
        sG[g * 5 + 3] = -LOG2E * w1;
        sG[g * 5 + 4] = -LOG2E * c0;
    } else if (t >= 64 && t < 64 + NR * NL) {
        const int idx = t - 64;
        const int r = idx >> 1, l = idx & 1;
        float acc = head_b[r * NL + l];
        #pragma unroll
        for (int v = 0; v < NV; ++v) {
            float bs = body_b[(r * NJ + 0) * NV + v] + body_b[(r * NJ + 1) * NV + v];
            acc = fmaf(head_W[(r * NL + l) * NV + v], bs, acc);
        }
        sC[idx] = acc;
    } else if (t >= 128 && t < 128 + NR * NL * NJ * NL) {
        const int idx = t - 128;
        const int lp = idx & 1, j = (idx >> 1) & 1, l = (idx >> 2) & 1, r = idx >> 3;
        float acc = 0.f;
        #pragma unroll
        for (int v = 0; v < NV; ++v)
            acc = fmaf(head_W[(r * NL + l) * NV + v],
                       body_W[((r * NJ + j) * NV + v) * NL + lp], acc);
        sM[idx] = acc;
    }
    __syncthreads();

    const int b = blockIdx.x * blockDim.x + t;
    if (b >= B) return;

    const float4* fp = (const float4*)(feat + (size_t)b * (NI * NL));
    float f0[NI], f1[NI];
    #pragma unroll
    for (int k = 0; k < 6; ++k) {
        float4 v = fp[k];
        f0[2 * k + 0] = v.x; f1[2 * k + 0] = v.y;
        f0[2 * k + 1] = v.z; f1[2 * k + 1] = v.w;
    }

    float o[NR * NL];
    #pragma unroll
    for (int r = 0; r < NR; ++r) {
        float o0 = sC[r * 2 + 0];
        float o1 = sC[r * 2 + 1];
        #pragma unroll
        for (int j = 0; j < NJ; ++j) {
            const int g = r * NJ + j;
            const v2f A0 = sG[g * 5 + 0];
            const v2f A1 = sG[g * 5 + 1];
            const v2f W0 = sG[g * 5 + 2];
            const v2f W1 = sG[g * 5 + 3];
            const v2f Cn = sG[g * 5 + 4];
            v2f den = 0.f, a0 = 0.f, a1 = 0.f;
            #pragma unroll
            for (int i = 0; i < NI; i += 2) {
                v2f X0 = { f0[i], f0[i + 1] };
                v2f X1 = { f1[i], f1[i + 1] };
                v2f n = __builtin_elementwise_fma(X0, __builtin_elementwise_fma(W0, X0, A0), Cn);
                n = __builtin_elementwise_fma(X1, __builtin_elementwise_fma(W1, X1, A1), n);
                v2f p = { __builtin_amdgcn_exp2f(n.x), __builtin_amdgcn_exp2f(n.y) };
                den += p;
                a0 = __builtin_elementwise_fma(p, X0, a0);
                a1 = __builtin_elementwise_fma(p, X1, a1);
            }
            float d = den.x + den.y;
            float rinv = __builtin_amdgcn_rcpf(d);
            float s0 = (a0.x + a0.y) * rinv;
            float s1 = (a1.x + a1.y) * rinv;
            const float m00 = sM[((r * 2 + 0) * 2 + j) * 2 + 0];
            const float m01 = sM[((r * 2 + 0) * 2 + j) * 2 + 1];
            const float m10 = sM[((r * 2 + 1) * 2 + j) * 2 + 0];
            const float m11 = sM[((r * 2 + 1) * 2 + j) * 2 + 1];
            o0 = fmaf(s0, m00, o0); o0 = fmaf(s1, m01, o0);
            o1 = fmaf(s0, m10, o1); o1 = fmaf(s1, m11, o1);
        }
        o[r * 2 + 0] = o0;
        o[r * 2 + 1] = o1;
    }

    float4* op = (float4*)(out + (size_t)b * (NR * NL));
    op[0] = make_float4(o[0], o[1], o[2], o[3]);
    op[1] = make_float4(o[4], o[5], o[6], o[7]);
    op[2] = make_float4(o[8], o[9], o[10], o[11]);
}

extern "C" void kernel_launch(void* const* d_in, const int* in_sizes, int n_in,
                              void* d_out, int out_size, void* d_ws, size_t ws_size,
                              hipStream_t stream) {
    (void)n_in; (void)out_size; (void)d_ws; (void)ws_size;
    const float* feat      = (const float*)d_in[0];
    const float* templates = (const float*)d_in[1];
    const float* gammas    = (const float*)d_in[2];
    const float* body_W    = (const float*)d_in[3];
    const float* body_b    = (const float*)d_in[4];
    const float* head_W    = (const float*)d_in[5];
    const float* head_b    = (const float*)d_in[6];
    float* out = (float*)d_out;

    int B = in_sizes[0] / (NI * NL);
    int blocks = (B + 255) / 256;
    hipLaunchKernelGGL(abstraction_fused, dim3(blocks), dim3(256), 0, stream,
                       feat, templates, gammas, body_W, body_b, head_W, head_b,
                       out, B);
}